// Round 1
// baseline (262.166 us; speedup 1.0000x reference)
//
#include <hip/hip_runtime.h>

#define Bb 2
#define Tt 2048
#define Cc_ 1024
#define Hh 16
#define HDd 64

typedef __attribute__((ext_vector_type(8))) short bf16x8;
typedef __attribute__((ext_vector_type(4))) float f32x4;
typedef __attribute__((ext_vector_type(4))) unsigned short u16x4;

__device__ __forceinline__ unsigned short f2bf(float f) {
  union { float f; unsigned int u; } v; v.f = f;
  unsigned int r = v.u + 0x7FFFu + ((v.u >> 16) & 1u);
  return (unsigned short)(r >> 16);
}
__device__ __forceinline__ float bf2f(unsigned short u) {
  union { unsigned int u; float f; } v; v.u = ((unsigned int)u) << 16;
  return v.f;
}
__device__ __forceinline__ f32x4 mfma16(bf16x8 a, bf16x8 b, f32x4 c) {
  return __builtin_amdgcn_mfma_f32_16x16x32_bf16(a, b, c, 0, 0, 0);
}
__device__ __forceinline__ void gl_lds16(const void* g, void* l) {
  auto* gp = reinterpret_cast<const __attribute__((address_space(1))) unsigned int*>(
      reinterpret_cast<unsigned long long>(g));
  auto* lp = reinterpret_cast<__attribute__((address_space(3))) unsigned int*>(
      reinterpret_cast<unsigned long long>(l));
  __builtin_amdgcn_global_load_lds(gp, lp, 16, 0, 0);
}

// ---------------- fp32 -> bf16 elementwise (x) ----------------
__global__ __launch_bounds__(256) void k_cvt(const float* __restrict__ in,
                                             unsigned short* __restrict__ out, int n4) {
  const int i = blockIdx.x * 256 + threadIdx.x;
  if (i >= n4) return;
  f32x4 v = ((const f32x4*)in)[i];
  u16x4 o;
  o[0] = f2bf(v[0]); o[1] = f2bf(v[1]); o[2] = f2bf(v[2]); o[3] = f2bf(v[3]);
  ((u16x4*)out)[i] = o;
}

// ---------------- fp32 [R][Cc] -> bf16 [Cc][R] transpose ----------------
__global__ __launch_bounds__(256) void k_tcvt(const float* __restrict__ in,
                                              unsigned short* __restrict__ out, int R, int Cc) {
  __shared__ float tile[32][33];
  const int c0 = blockIdx.x * 32, r0 = blockIdx.y * 32;
  const int tx = threadIdx.x, ty = threadIdx.y;  // (32,8)
#pragma unroll
  for (int i = 0; i < 4; ++i)
    tile[ty + i * 8][tx] = in[(size_t)(r0 + ty + i * 8) * Cc + c0 + tx];
  __syncthreads();
#pragma unroll
  for (int i = 0; i < 4; ++i)
    out[(size_t)(c0 + ty + i * 8) * R + r0 + tx] = f2bf(tile[tx][ty + i * 8]);
}

// ---------------- bf16 GEMM: C[M][N] = A[M][K] * Bt[N][K]^T ----------------
template <bool OUT_BF16>
__global__ __launch_bounds__(256) void k_gemm(const unsigned short* __restrict__ A,
                                              const unsigned short* __restrict__ Bt,
                                              void* __restrict__ Cout, int M, int N, int K) {
  __shared__ unsigned short lA[128 * 64];
  __shared__ unsigned short lB[128 * 64];
  const int tid = threadIdx.x;
  const int lane = tid & 63, wid = tid >> 6;
  const int wr = wid >> 1, wc = wid & 1;
  const int bm = blockIdx.y * 128, bn = blockIdx.x * 128;
  const int l15 = lane & 15, l4 = lane >> 4;
  f32x4 acc[4][4];
#pragma unroll
  for (int i = 0; i < 4; ++i)
#pragma unroll
    for (int j = 0; j < 4; ++j) acc[i][j] = f32x4{0.f, 0.f, 0.f, 0.f};
  const int nk = K >> 6;
  for (int t = 0; t < nk; ++t) {
    const int k0 = t << 6;
    __syncthreads();
#pragma unroll
    for (int i = 0; i < 4; ++i) {
      const int slot = i * 256 + tid;
      const int row = slot >> 3, g = slot & 7;
      const int gs = (g ^ (row & 7)) * 8;
      gl_lds16(A + (size_t)(bm + row) * K + k0 + gs, &lA[slot * 8]);
      gl_lds16(Bt + (size_t)(bn + row) * K + k0 + gs, &lB[slot * 8]);
    }
    __syncthreads();
#pragma unroll
    for (int ks = 0; ks < 2; ++ks) {
      bf16x8 af[4], bfr[4];
#pragma unroll
      for (int mf = 0; mf < 4; ++mf) {
        const int row = wr * 64 + mf * 16 + l15;
        const int g = ks * 4 + l4;
        af[mf] = *(const bf16x8*)&lA[row * 64 + ((g ^ (row & 7)) * 8)];
      }
#pragma unroll
      for (int nf = 0; nf < 4; ++nf) {
        const int row = wc * 64 + nf * 16 + l15;
        const int g = ks * 4 + l4;
        bfr[nf] = *(const bf16x8*)&lB[row * 64 + ((g ^ (row & 7)) * 8)];
      }
#pragma unroll
      for (int mf = 0; mf < 4; ++mf)
#pragma unroll
        for (int nf = 0; nf < 4; ++nf)
          acc[mf][nf] = mfma16(af[mf], bfr[nf], acc[mf][nf]);
    }
  }
  const int rb = bm + wr * 64 + l4 * 4;
  const int cb = bn + wc * 64 + l15;
#pragma unroll
  for (int mf = 0; mf < 4; ++mf)
#pragma unroll
    for (int nf = 0; nf < 4; ++nf)
#pragma unroll
      for (int j = 0; j < 4; ++j) {
        const size_t idx = (size_t)(rb + mf * 16 + j) * N + cb + nf * 16;
        if (OUT_BF16)
          ((unsigned short*)Cout)[idx] = f2bf(acc[mf][nf][j]);
        else
          ((float*)Cout)[idx] = acc[mf][nf][j];
      }
}

// ---------------- RoPE + repack Q,K to [B,H,T,64] bf16 (Q pre-scaled 1/8) ----------------
__global__ __launch_bounds__(256) void k_rope(const unsigned short* __restrict__ qkv,
                                              const float* __restrict__ rsin,
                                              const float* __restrict__ rcos,
                                              unsigned short* __restrict__ Q,
                                              unsigned short* __restrict__ K) {
  const int tid = blockIdx.x * 256 + threadIdx.x;  // 2^21 total
  const int d = tid & 31;
  const int t = (tid >> 5) & 2047;
  const int h = (tid >> 16) & 15;
  const int b = tid >> 20;
  const size_t rq = (size_t)(b * Tt + t) * 3072 + h * 192;
  const float q1 = bf2f(qkv[rq + d]), q2 = bf2f(qkv[rq + 32 + d]);
  const float k1 = bf2f(qkv[rq + 64 + d]), k2 = bf2f(qkv[rq + 96 + d]);
  const float s = rsin[t * 32 + d], c = rcos[t * 32 + d];
  const size_t ob = ((size_t)(b * Hh + h) * Tt + t) * 64 + d;
  Q[ob] = f2bf((q1 * c - q2 * s) * 0.125f);
  Q[ob + 32] = f2bf((q1 * s + q2 * c) * 0.125f);
  K[ob] = f2bf(k1 * c - k2 * s);
  K[ob + 32] = f2bf(k1 * s + k2 * c);
}

// ---------------- V repack: qkv v-cols -> Vt [B*H][64][T] bf16 ----------------
__global__ __launch_bounds__(256) void k_vrep(const unsigned short* __restrict__ qkv,
                                              unsigned short* __restrict__ Vt) {
  __shared__ unsigned short tile[32][72];
  const int bh = blockIdx.y;
  const int t0 = blockIdx.x * 32;
  const int tx = threadIdx.x, ty = threadIdx.y;  // (32,8)
  const int b = bh >> 4, h = bh & 15;
#pragma unroll
  for (int i = 0; i < 4; ++i) {
    const int trow = ty + i * 8;
    const size_t r = (size_t)(b * Tt + t0 + trow) * 3072 + h * 192 + 128;
    tile[trow][tx] = qkv[r + tx];
    tile[trow][tx + 32] = qkv[r + 32 + tx];
  }
  __syncthreads();
#pragma unroll
  for (int i = 0; i < 8; ++i) {
    const int d = ty + i * 8;
    Vt[((size_t)bh * 64 + d) * Tt + t0 + tx] = tile[tx][d];
  }
}

// ---------------- causal flash attention ----------------
// grid (32 qtiles, 32 bh), 256 thr. Q [BH][T][64] (pre-scaled), K same, Vt [BH][64][T].
__global__ __launch_bounds__(256) void k_attn(const unsigned short* __restrict__ Q,
                                              const unsigned short* __restrict__ Kt,
                                              const unsigned short* __restrict__ Vt,
                                              unsigned short* __restrict__ Aout) {
  __shared__ unsigned short lK[64 * 64];
  __shared__ unsigned short lV[64 * 64];
  __shared__ unsigned short lP[4][16 * 64];
  const int qt = blockIdx.x, bh = blockIdx.y;
  const int b = bh >> 4, h = bh & 15;
  const int tid = threadIdx.x, lane = tid & 63, w = tid >> 6;
  const int qb = qt * 64;
  const int l15 = lane & 15, l4 = lane >> 4;
  const size_t qoff = ((size_t)bh * Tt + qb + w * 16 + l15) * 64 + l4 * 8;
  const bf16x8 qf0 = *(const bf16x8*)&Q[qoff];
  const bf16x8 qf1 = *(const bf16x8*)&Q[qoff + 32];
  f32x4 o[4];
#pragma unroll
  for (int i = 0; i < 4; ++i) o[i] = f32x4{0.f, 0.f, 0.f, 0.f};
  float mrun[4] = {-1e30f, -1e30f, -1e30f, -1e30f};
  float lrun[4] = {0.f, 0.f, 0.f, 0.f};
  const unsigned short* Kbh = Kt + (size_t)bh * Tt * 64;
  const unsigned short* Vbh = Vt + (size_t)bh * 64 * Tt;
  const int nt = qt + 1;
  for (int t = 0; t < nt; ++t) {
    const int kv0 = t * 64;
    __syncthreads();
#pragma unroll
    for (int i = 0; i < 2; ++i) {
      const int slot = i * 256 + tid;
      const int row = slot >> 3, g = slot & 7;
      const int gs = (g ^ (row & 7)) * 8;
      gl_lds16(Kbh + (size_t)(kv0 + row) * 64 + gs, &lK[slot * 8]);
      gl_lds16(Vbh + (size_t)row * Tt + kv0 + gs, &lV[slot * 8]);
    }
    __syncthreads();
    f32x4 s[4];
#pragma unroll
    for (int i = 0; i < 4; ++i) s[i] = f32x4{0.f, 0.f, 0.f, 0.f};
#pragma unroll
    for (int ks = 0; ks < 2; ++ks) {
      const bf16x8 qa = ks ? qf1 : qf0;
#pragma unroll
      for (int nf = 0; nf < 4; ++nf) {
        const int row = nf * 16 + l15;
        const int g = ks * 4 + l4;
        const bf16x8 kf = *(const bf16x8*)&lK[row * 64 + ((g ^ (row & 7)) * 8)];
        s[nf] = mfma16(qa, kf, s[nf]);
      }
    }
    if (kv0 == qb) {  // diagonal tile: causal mask
#pragma unroll
      for (int nf = 0; nf < 4; ++nf) {
        const int key = kv0 + nf * 16 + l15;
#pragma unroll
        for (int j = 0; j < 4; ++j) {
          const int qrow = qb + w * 16 + l4 * 4 + j;
          if (key > qrow) s[nf][j] = -3e38f;
        }
      }
    }
    float tmax[4], mnew[4], alpha[4], ps[4];
#pragma unroll
    for (int j = 0; j < 4; ++j)
      tmax[j] = fmaxf(fmaxf(s[0][j], s[1][j]), fmaxf(s[2][j], s[3][j]));
#pragma unroll
    for (int off = 1; off < 16; off <<= 1)
#pragma unroll
      for (int j = 0; j < 4; ++j)
        tmax[j] = fmaxf(tmax[j], __shfl_xor(tmax[j], off, 64));
#pragma unroll
    for (int j = 0; j < 4; ++j) {
      mnew[j] = fmaxf(mrun[j], tmax[j]);
      alpha[j] = __expf(mrun[j] - mnew[j]);
      ps[j] = 0.f;
    }
#pragma unroll
    for (int nf = 0; nf < 4; ++nf) {
#pragma unroll
      for (int j = 0; j < 4; ++j) {
        const float p = __expf(s[nf][j] - mnew[j]);
        ps[j] += p;
        const int r = l4 * 4 + j;
        const int key = nf * 16 + l15;
        lP[w][r * 64 + (((key >> 3) ^ (r & 7)) * 8) + (key & 7)] = f2bf(p);
      }
    }
#pragma unroll
    for (int off = 1; off < 16; off <<= 1)
#pragma unroll
      for (int j = 0; j < 4; ++j) ps[j] += __shfl_xor(ps[j], off, 64);
#pragma unroll
    for (int j = 0; j < 4; ++j) {
      lrun[j] = lrun[j] * alpha[j] + ps[j];
      mrun[j] = mnew[j];
    }
#pragma unroll
    for (int df = 0; df < 4; ++df)
#pragma unroll
      for (int j = 0; j < 4; ++j) o[df][j] *= alpha[j];
#pragma unroll
    for (int kb = 0; kb < 2; ++kb) {
      const int pr = l15;
      const int g = kb * 4 + l4;
      const bf16x8 pa = *(const bf16x8*)&lP[w][pr * 64 + ((g ^ (pr & 7)) * 8)];
#pragma unroll
      for (int df = 0; df < 4; ++df) {
        const int row = df * 16 + l15;
        const bf16x8 vb = *(const bf16x8*)&lV[row * 64 + ((g ^ (row & 7)) * 8)];
        o[df] = mfma16(pa, vb, o[df]);
      }
    }
  }
#pragma unroll
  for (int j = 0; j < 4; ++j) {
    const float inv = 1.f / lrun[j];
    const size_t rr = (size_t)(b * Tt + qb + w * 16 + l4 * 4 + j) * 1024 + h * 64 + l15;
#pragma unroll
    for (int df = 0; df < 4; ++df) Aout[rr + df * 16] = f2bf(o[df][j] * inv);
  }
}

extern "C" void kernel_launch(void* const* d_in, const int* in_sizes, int n_in,
                              void* d_out, int out_size, void* d_ws, size_t ws_size,
                              hipStream_t stream) {
  const float* x = (const float*)d_in[0];
  const float* Wqkv = (const float*)d_in[1];
  const float* Wproj = (const float*)d_in[2];
  const float* rsin = (const float*)d_in[3];
  const float* rcos = (const float*)d_in[4];
  float* out = (float*)d_out;
  char* ws = (char*)d_ws;
  // ws layout (MB): xb 0-8, wqkvt 8-14, wprot 14-16, qkv 16-40, Q 40-48, K 48-56, Vt 56-64, attn 64-72
  unsigned short* xb = (unsigned short*)(ws);
  unsigned short* wqkvt = (unsigned short*)(ws + (size_t)(8 << 20));
  unsigned short* wprot = (unsigned short*)(ws + (size_t)(14 << 20));
  unsigned short* qkv = (unsigned short*)(ws + (size_t)(16 << 20));
  unsigned short* Q = (unsigned short*)(ws + (size_t)(40 << 20));
  unsigned short* K = (unsigned short*)(ws + (size_t)(48 << 20));
  unsigned short* Vt = (unsigned short*)(ws + (size_t)(56 << 20));
  unsigned short* attn = (unsigned short*)(ws + (size_t)(64 << 20));

  k_cvt<<<4096, 256, 0, stream>>>(x, xb, 1048576);
  k_tcvt<<<dim3(96, 32), dim3(32, 8), 0, stream>>>(Wqkv, wqkvt, 1024, 3072);
  k_tcvt<<<dim3(32, 32), dim3(32, 8), 0, stream>>>(Wproj, wprot, 1024, 1024);
  k_gemm<true><<<dim3(24, 32), 256, 0, stream>>>(xb, wqkvt, qkv, 4096, 3072, 1024);
  k_rope<<<8192, 256, 0, stream>>>(qkv, rsin, rcos, Q, K);
  k_vrep<<<dim3(64, 32), dim3(32, 8), 0, stream>>>(qkv, Vt);
  k_attn<<<dim3(32, 32), 256, 0, stream>>>(Q, K, Vt, attn);
  k_gemm<false><<<dim3(8, 32), 256, 0, stream>>>(attn, wprot, out, 4096, 1024, 1024);
}

// Round 2
// 202.792 us; speedup vs baseline: 1.2928x; 1.2928x over previous
//
#include <hip/hip_runtime.h>

#define Bb 2
#define Tt 2048
#define Cc_ 1024
#define Hh 16
#define HDd 64

typedef __attribute__((ext_vector_type(8))) short bf16x8;
typedef __attribute__((ext_vector_type(4))) float f32x4;
typedef __attribute__((ext_vector_type(4))) unsigned short u16x4;

__device__ __forceinline__ unsigned short f2bf(float f) {
  union { float f; unsigned int u; } v; v.f = f;
  unsigned int r = v.u + 0x7FFFu + ((v.u >> 16) & 1u);
  return (unsigned short)(r >> 16);
}
__device__ __forceinline__ float bf2f(unsigned short u) {
  union { unsigned int u; float f; } v; v.u = ((unsigned int)u) << 16;
  return v.f;
}
__device__ __forceinline__ f32x4 mfma16(bf16x8 a, bf16x8 b, f32x4 c) {
  return __builtin_amdgcn_mfma_f32_16x16x32_bf16(a, b, c, 0, 0, 0);
}
__device__ __forceinline__ void gl_lds16(const void* g, void* l) {
  auto* gp = reinterpret_cast<const __attribute__((address_space(1))) unsigned int*>(
      reinterpret_cast<unsigned long long>(g));
  auto* lp = reinterpret_cast<__attribute__((address_space(3))) unsigned int*>(
      reinterpret_cast<unsigned long long>(l));
  __builtin_amdgcn_global_load_lds(gp, lp, 16, 0, 0);
}

// ---------------- fp32 -> bf16 elementwise (x) ----------------
__global__ __launch_bounds__(256) void k_cvt(const float* __restrict__ in,
                                             unsigned short* __restrict__ out, int n4) {
  const int i = blockIdx.x * 256 + threadIdx.x;
  if (i >= n4) return;
  f32x4 v = ((const f32x4*)in)[i];
  u16x4 o;
  o[0] = f2bf(v[0]); o[1] = f2bf(v[1]); o[2] = f2bf(v[2]); o[3] = f2bf(v[3]);
  ((u16x4*)out)[i] = o;
}

// ---------------- fp32 [R][Cc] -> bf16 [Cc][R] transpose ----------------
__global__ __launch_bounds__(256) void k_tcvt(const float* __restrict__ in,
                                              unsigned short* __restrict__ out, int R, int Cc) {
  __shared__ float tile[32][33];
  const int c0 = blockIdx.x * 32, r0 = blockIdx.y * 32;
  const int tx = threadIdx.x, ty = threadIdx.y;  // (32,8)
#pragma unroll
  for (int i = 0; i < 4; ++i)
    tile[ty + i * 8][tx] = in[(size_t)(r0 + ty + i * 8) * Cc + c0 + tx];
  __syncthreads();
#pragma unroll
  for (int i = 0; i < 4; ++i)
    out[(size_t)(c0 + ty + i * 8) * R + r0 + tx] = f2bf(tile[tx][ty + i * 8]);
}

// ---------------- bf16 GEMM: C[M][N] = A[M][K] * Bt[N][K]^T ----------------
template <bool OUT_BF16>
__global__ __launch_bounds__(256) void k_gemm(const unsigned short* __restrict__ A,
                                              const unsigned short* __restrict__ Bt,
                                              void* __restrict__ Cout, int M, int N, int K) {
  __shared__ unsigned short lA[128 * 64];
  __shared__ unsigned short lB[128 * 64];
  const int tid = threadIdx.x;
  const int lane = tid & 63, wid = tid >> 6;
  const int wr = wid >> 1, wc = wid & 1;
  const int bm = blockIdx.y * 128, bn = blockIdx.x * 128;
  const int l15 = lane & 15, l4 = lane >> 4;
  f32x4 acc[4][4];
#pragma unroll
  for (int i = 0; i < 4; ++i)
#pragma unroll
    for (int j = 0; j < 4; ++j) acc[i][j] = f32x4{0.f, 0.f, 0.f, 0.f};
  const int nk = K >> 6;
  for (int t = 0; t < nk; ++t) {
    const int k0 = t << 6;
    __syncthreads();
#pragma unroll
    for (int i = 0; i < 4; ++i) {
      const int slot = i * 256 + tid;
      const int row = slot >> 3, g = slot & 7;
      const int gs = (g ^ (row & 7)) * 8;
      gl_lds16(A + (size_t)(bm + row) * K + k0 + gs, &lA[slot * 8]);
      gl_lds16(Bt + (size_t)(bn + row) * K + k0 + gs, &lB[slot * 8]);
    }
    __syncthreads();
#pragma unroll
    for (int ks = 0; ks < 2; ++ks) {
      bf16x8 af[4], bfr[4];
#pragma unroll
      for (int mf = 0; mf < 4; ++mf) {
        const int row = wr * 64 + mf * 16 + l15;
        const int g = ks * 4 + l4;
        af[mf] = *(const bf16x8*)&lA[row * 64 + ((g ^ (row & 7)) * 8)];
      }
#pragma unroll
      for (int nf = 0; nf < 4; ++nf) {
        const int row = wc * 64 + nf * 16 + l15;
        const int g = ks * 4 + l4;
        bfr[nf] = *(const bf16x8*)&lB[row * 64 + ((g ^ (row & 7)) * 8)];
      }
#pragma unroll
      for (int mf = 0; mf < 4; ++mf)
#pragma unroll
        for (int nf = 0; nf < 4; ++nf)
          acc[mf][nf] = mfma16(af[mf], bfr[nf], acc[mf][nf]);
    }
  }
  const int rb = bm + wr * 64 + l4 * 4;
  const int cb = bn + wc * 64 + l15;
#pragma unroll
  for (int mf = 0; mf < 4; ++mf)
#pragma unroll
    for (int nf = 0; nf < 4; ++nf)
#pragma unroll
      for (int j = 0; j < 4; ++j) {
        const size_t idx = (size_t)(rb + mf * 16 + j) * N + cb + nf * 16;
        if (OUT_BF16)
          ((unsigned short*)Cout)[idx] = f2bf(acc[mf][nf][j]);
        else
          ((float*)Cout)[idx] = acc[mf][nf][j];
      }
}

// ---------------- RoPE + repack Q,K to [B,H,T,64] bf16 (Q pre-scaled 1/8) ----------------
__global__ __launch_bounds__(256) void k_rope(const unsigned short* __restrict__ qkv,
                                              const float* __restrict__ rsin,
                                              const float* __restrict__ rcos,
                                              unsigned short* __restrict__ Q,
                                              unsigned short* __restrict__ K) {
  const int tid = blockIdx.x * 256 + threadIdx.x;  // 2^21 total
  const int d = tid & 31;
  const int t = (tid >> 5) & 2047;
  const int h = (tid >> 16) & 15;
  const int b = tid >> 20;
  const size_t rq = (size_t)(b * Tt + t) * 3072 + h * 192;
  const float q1 = bf2f(qkv[rq + d]), q2 = bf2f(qkv[rq + 32 + d]);
  const float k1 = bf2f(qkv[rq + 64 + d]), k2 = bf2f(qkv[rq + 96 + d]);
  const float s = rsin[t * 32 + d], c = rcos[t * 32 + d];
  const size_t ob = ((size_t)(b * Hh + h) * Tt + t) * 64 + d;
  Q[ob] = f2bf((q1 * c - q2 * s) * 0.125f);
  Q[ob + 32] = f2bf((q1 * s + q2 * c) * 0.125f);
  K[ob] = f2bf(k1 * c - k2 * s);
  K[ob + 32] = f2bf(k1 * s + k2 * c);
}

// ---------------- V repack: qkv v-cols -> Vt [B*H][64][T] bf16 ----------------
__global__ __launch_bounds__(256) void k_vrep(const unsigned short* __restrict__ qkv,
                                              unsigned short* __restrict__ Vt) {
  __shared__ unsigned short tile[32][72];
  const int bh = blockIdx.y;
  const int t0 = blockIdx.x * 32;
  const int tx = threadIdx.x, ty = threadIdx.y;  // (32,8)
  const int b = bh >> 4, h = bh & 15;
#pragma unroll
  for (int i = 0; i < 4; ++i) {
    const int trow = ty + i * 8;
    const size_t r = (size_t)(b * Tt + t0 + trow) * 3072 + h * 192 + 128;
    tile[trow][tx] = qkv[r + tx];
    tile[trow][tx + 32] = qkv[r + 32 + tx];
  }
  __syncthreads();
#pragma unroll
  for (int i = 0; i < 8; ++i) {
    const int d = ty + i * 8;
    Vt[((size_t)bh * 64 + d) * Tt + t0 + tx] = tile[tx][d];
  }
}

// ---------------- causal flash attention (paired qtiles, swapped-QK softmax) ----------------
// grid (16 qtile-pairs, 32 bh), 256 thr. Q [BH][T][64] (pre-scaled), K same, Vt [BH][64][T].
// Each block handles qtiles {31-bx, bx}: constant 33 tile-steps -> CU-balanced.
// Swapped QK^T (mfma(K,Q)): lane holds 16 scores of q-row l15 -> in-lane reduce + 2 shfl.
__global__ __launch_bounds__(256) void k_attn(const unsigned short* __restrict__ Q,
                                              const unsigned short* __restrict__ Kt,
                                              const unsigned short* __restrict__ Vt,
                                              unsigned short* __restrict__ Aout) {
  __shared__ unsigned short lK[64 * 64];
  __shared__ unsigned short lV[64 * 64];
  __shared__ unsigned short lP[4][16 * 64];
  const int bxq = blockIdx.x, bh = blockIdx.y;
  const int b = bh >> 4, h = bh & 15;
  const int tid = threadIdx.x, lane = tid & 63, w = tid >> 6;
  const int l15 = lane & 15, l4 = lane >> 4;
  const unsigned short* Kbh = Kt + (size_t)bh * Tt * 64;
  const unsigned short* Vbh = Vt + (size_t)bh * 64 * Tt;
  unsigned short* lPw = lP[w];
  for (int ph = 0; ph < 2; ++ph) {
    const int qt = ph ? bxq : (31 - bxq);
    const int qb = qt * 64;
    const size_t qoff = ((size_t)bh * Tt + qb + w * 16 + l15) * 64 + l4 * 8;
    const bf16x8 qf0 = *(const bf16x8*)&Q[qoff];
    const bf16x8 qf1 = *(const bf16x8*)&Q[qoff + 32];
    f32x4 o[4];
#pragma unroll
    for (int i = 0; i < 4; ++i) o[i] = f32x4{0.f, 0.f, 0.f, 0.f};
    float mrun = -1e30f, lrun = 0.f;  // stats for q-row (w*16 + l15)
    const int nt = qt + 1;
    for (int t = 0; t < nt; ++t) {
      const int kv0 = t * 64;
      __syncthreads();
#pragma unroll
      for (int i = 0; i < 2; ++i) {
        const int slot = i * 256 + tid;
        const int row = slot >> 3, g = slot & 7;
        const int gs = (g ^ (row & 7)) * 8;
        gl_lds16(Kbh + (size_t)(kv0 + row) * 64 + gs, &lK[slot * 8]);
        gl_lds16(Vbh + (size_t)row * Tt + kv0 + gs, &lV[slot * 8]);
      }
      __syncthreads();
      // s[nf][j]: key = kv0 + nf*16 + l4*4 + j, qrow = qb + w*16 + l15
      f32x4 s[4];
#pragma unroll
      for (int i = 0; i < 4; ++i) s[i] = f32x4{0.f, 0.f, 0.f, 0.f};
      __builtin_amdgcn_s_setprio(1);
#pragma unroll
      for (int ks = 0; ks < 2; ++ks) {
        const bf16x8 qa = ks ? qf1 : qf0;
#pragma unroll
        for (int nf = 0; nf < 4; ++nf) {
          const int row = nf * 16 + l15;
          const int g = ks * 4 + l4;
          const bf16x8 kf = *(const bf16x8*)&lK[row * 64 + ((g ^ (row & 7)) * 8)];
          s[nf] = mfma16(kf, qa, s[nf]);
        }
      }
      __builtin_amdgcn_s_setprio(0);
      if (kv0 == qb) {  // diagonal tile: causal mask (key > qrow)
#pragma unroll
        for (int nf = 0; nf < 4; ++nf)
#pragma unroll
          for (int j = 0; j < 4; ++j)
            if (nf * 16 + l4 * 4 + j > w * 16 + l15) s[nf][j] = -3e38f;
      }
      // row max: 15 in-lane fmax + 2 cross-l4 shfl
      float mx = s[0][0];
#pragma unroll
      for (int nf = 0; nf < 4; ++nf)
#pragma unroll
        for (int j = 0; j < 4; ++j)
          if (nf | j) mx = fmaxf(mx, s[nf][j]);
      mx = fmaxf(mx, __shfl_xor(mx, 16, 64));
      mx = fmaxf(mx, __shfl_xor(mx, 32, 64));
      const bool need = !__all(mx - mrun <= 8.0f);  // T13 defer-max
      float mnew = mrun;
      if (need) mnew = fmaxf(mrun, mx);
      float ssum = 0.f;
#pragma unroll
      for (int nf = 0; nf < 4; ++nf) {
        u16x4 pk;
#pragma unroll
        for (int j = 0; j < 4; ++j) {
          const float p = __expf(s[nf][j] - mnew);
          ssum += p;
          pk[j] = f2bf(p);
        }
        const int g0 = nf * 2 + (l4 >> 1);
        *(u16x4*)&lPw[l15 * 64 + ((g0 ^ (l15 & 7)) * 8) + (l4 & 1) * 4] = pk;
      }
      ssum += __shfl_xor(ssum, 16, 64);
      ssum += __shfl_xor(ssum, 32, 64);
      if (need) {
        const float alpha = __expf(mrun - mnew);
        lrun = lrun * alpha + ssum;
        mrun = mnew;
        float aj[4];
#pragma unroll
        for (int j = 0; j < 4; ++j) aj[j] = __shfl(alpha, l4 * 4 + j, 64);
#pragma unroll
        for (int df = 0; df < 4; ++df)
#pragma unroll
          for (int j = 0; j < 4; ++j) o[df][j] *= aj[j];
      } else {
        lrun += ssum;
      }
      __builtin_amdgcn_s_setprio(1);
#pragma unroll
      for (int kb = 0; kb < 2; ++kb) {
        const bf16x8 pa = *(const bf16x8*)&lPw[l15 * 64 + (((kb * 4 + l4) ^ (l15 & 7)) * 8)];
#pragma unroll
        for (int df = 0; df < 4; ++df) {
          const int row = df * 16 + l15;
          const int g = kb * 4 + l4;
          const bf16x8 vb = *(const bf16x8*)&lV[row * 64 + ((g ^ (row & 7)) * 8)];
          o[df] = mfma16(pa, vb, o[df]);
        }
      }
      __builtin_amdgcn_s_setprio(0);
    }
    const float rinv = 1.f / lrun;
    float lj[4];
#pragma unroll
    for (int j = 0; j < 4; ++j) lj[j] = __shfl(rinv, l4 * 4 + j, 64);
#pragma unroll
    for (int j = 0; j < 4; ++j) {
      const size_t rr = (size_t)(b * Tt + qb + w * 16 + l4 * 4 + j) * 1024 + h * 64 + l15;
#pragma unroll
      for (int df = 0; df < 4; ++df) Aout[rr + df * 16] = f2bf(o[df][j] * lj[j]);
    }
  }
}

extern "C" void kernel_launch(void* const* d_in, const int* in_sizes, int n_in,
                              void* d_out, int out_size, void* d_ws, size_t ws_size,
                              hipStream_t stream) {
  const float* x = (const float*)d_in[0];
  const float* Wqkv = (const float*)d_in[1];
  const float* Wproj = (const float*)d_in[2];
  const float* rsin = (const float*)d_in[3];
  const float* rcos = (const float*)d_in[4];
  float* out = (float*)d_out;
  char* ws = (char*)d_ws;
  // ws layout (MB): xb 0-8, wqkvt 8-14, wprot 14-16, qkv 16-40, Q 40-48, K 48-56, Vt 56-64, attn 64-72
  unsigned short* xb = (unsigned short*)(ws);
  unsigned short* wqkvt = (unsigned short*)(ws + (size_t)(8 << 20));
  unsigned short* wprot = (unsigned short*)(ws + (size_t)(14 << 20));
  unsigned short* qkv = (unsigned short*)(ws + (size_t)(16 << 20));
  unsigned short* Q = (unsigned short*)(ws + (size_t)(40 << 20));
  unsigned short* K = (unsigned short*)(ws + (size_t)(48 << 20));
  unsigned short* Vt = (unsigned short*)(ws + (size_t)(56 << 20));
  unsigned short* attn = (unsigned short*)(ws + (size_t)(64 << 20));

  k_cvt<<<4096, 256, 0, stream>>>(x, xb, 1048576);
  k_tcvt<<<dim3(96, 32), dim3(32, 8), 0, stream>>>(Wqkv, wqkvt, 1024, 3072);
  k_tcvt<<<dim3(32, 32), dim3(32, 8), 0, stream>>>(Wproj, wprot, 1024, 1024);
  k_gemm<true><<<dim3(24, 32), 256, 0, stream>>>(xb, wqkvt, qkv, 4096, 3072, 1024);
  k_rope<<<8192, 256, 0, stream>>>(qkv, rsin, rcos, Q, K);
  k_vrep<<<dim3(64, 32), dim3(32, 8), 0, stream>>>(qkv, Vt);
  k_attn<<<dim3(16, 32), 256, 0, stream>>>(Q, K, Vt, attn);
  k_gemm<false><<<dim3(8, 32), 256, 0, stream>>>(attn, wprot, out, 4096, 1024, 1024);
}